// Round 4
// baseline (146.102 us; speedup 1.0000x reference)
//
#include <hip/hip_runtime.h>

#define CTX_T 768
#define CDIM  1024
#define BDIM  8
#define MTOT  (BDIM * CTX_T)   // 6144

typedef __attribute__((ext_vector_type(8))) __bf16 bf16x8;
typedef __attribute__((ext_vector_type(8))) short short8;
typedef __attribute__((ext_vector_type(4))) float f32x4;

__device__ inline unsigned short f2bf(float f) {
    union { float f; unsigned u; } v; v.f = f;
    unsigned r = v.u + 0x7fffu + ((v.u >> 16) & 1u);
    return (unsigned short)(r >> 16);
}
__device__ inline float bf2f(unsigned short u) {
    union { unsigned u; float f; } v; v.u = ((unsigned)u) << 16; return v.f;
}

// ---- fused f32 -> bf16 converter for the 4 weight matrices ----
__global__ void cvt4(const float* __restrict__ s0, const float* __restrict__ s1,
                     const float* __restrict__ s2, const float* __restrict__ s3,
                     unsigned short* __restrict__ d) {
    int i = (blockIdx.x * blockDim.x + threadIdx.x) * 4;
    const int SEG = 1 << 20;
    const float* s = (i < SEG) ? s0 : (i < 2 * SEG) ? s1 : (i < 3 * SEG) ? s2 : s3;
    float4 f = *(const float4*)(s + (i & (SEG - 1)));
    ushort4 o;
    o.x = f2bf(f.x); o.y = f2bf(f.y); o.z = f2bf(f.z); o.w = f2bf(f.w);
    *(ushort4*)(d + i) = o;
}

// ---- time-shift + mix, f32 in -> bf16 out ----
__global__ void mix_bf16(const float* __restrict__ x, const float* __restrict__ tm,
                         unsigned short* __restrict__ xm, int total) {
    int i = (blockIdx.x * blockDim.x + threadIdx.x) * 4;
    if (i >= total) return;
    int c  = i & (CDIM - 1);
    int bt = i >> 10;
    int t  = bt % CTX_T;
    float4 xc  = *(const float4*)(x + i);
    float4 tmc = *(const float4*)(tm + c);
    float4 xp = make_float4(0.f, 0.f, 0.f, 0.f);
    if (t > 0) xp = *(const float4*)(x + i - CDIM);
    ushort4 o;
    o.x = f2bf(xc.x * tmc.x + xp.x * (1.f - tmc.x));
    o.y = f2bf(xc.y * tmc.y + xp.y * (1.f - tmc.y));
    o.z = f2bf(xc.z * tmc.z + xp.z * (1.f - tmc.z));
    o.w = f2bf(xc.w * tmc.w + xp.w * (1.f - tmc.w));
    *(ushort4*)(xm + i) = o;
}

#define GLL16(GP, LP) __builtin_amdgcn_global_load_lds(                        \
    (__attribute__((address_space(1))) void*)(void*)(GP),                     \
    (__attribute__((address_space(3))) void*)(void*)(LP), 16, 0, 0)

// ================= fallback 128x128 GEMM (proven R3) =================
template <int MODE>
__global__ __launch_bounds__(256) void gemm_bt(const unsigned short* __restrict__ A,
                                               const unsigned short* __restrict__ Bw,
                                               void* __restrict__ Cout,
                                               int ldc, int K) {
    __shared__ unsigned short lA[128 * 32];
    __shared__ unsigned short lB[128 * 32];
    const int tid  = threadIdx.x;
    const int lane = tid & 63;
    const int wid  = tid >> 6;
    const int wr   = wid >> 1, wc = wid & 1;
    const size_t m0 = (size_t)blockIdx.x * 128;
    const size_t n0 = (size_t)blockIdx.y * 128;

    const unsigned short* gA = A + (m0 + (size_t)(tid >> 2)) * K + ((tid & 3) << 3);
    const unsigned short* gB = Bw + (n0 + (size_t)(tid >> 2)) * K + ((tid & 3) << 3);
    char* sA = (char*)lA + tid * 16;
    char* sB = (char*)lB + tid * 16;

    f32x4 acc[4][4] = {};

    for (int k0 = 0; k0 < K; k0 += 32) {
        GLL16(gA + k0,             sA);
        GLL16(gA + k0 + 64 * K,    sA + 4096);
        GLL16(gB + k0,             sB);
        GLL16(gB + k0 + 64 * K,    sB + 4096);
        __syncthreads();

        const unsigned short* pA = lA + (wr * 64 + (lane & 15)) * 32 + ((lane >> 4) << 3);
        const unsigned short* pB = lB + (wc * 64 + (lane & 15)) * 32 + ((lane >> 4) << 3);
        bf16x8 a[4], b[4];
#pragma unroll
        for (int i = 0; i < 4; i++) {
            a[i] = __builtin_bit_cast(bf16x8, *(const short8*)(pA + i * 16 * 32));
            b[i] = __builtin_bit_cast(bf16x8, *(const short8*)(pB + i * 16 * 32));
        }
#pragma unroll
        for (int i = 0; i < 4; i++)
#pragma unroll
            for (int j = 0; j < 4; j++)
                acc[i][j] = __builtin_amdgcn_mfma_f32_16x16x32_bf16(a[i], b[j], acc[i][j], 0, 0, 0);
        __syncthreads();
    }

    const int region = (int)(m0 >> 10);
#pragma unroll
    for (int i = 0; i < 4; i++) {
#pragma unroll
        for (int j = 0; j < 4; j++) {
            size_t row = m0 + wr * 64 + i * 16 + ((lane >> 4) << 2);
            size_t col = n0 + wc * 64 + j * 16 + (lane & 15);
            if constexpr (MODE == 0) {
                float* Cp = (float*)Cout + row * (size_t)ldc + col;
#pragma unroll
                for (int q = 0; q < 4; q++) Cp[(size_t)q * ldc] = acc[i][j][q];
            } else {
                unsigned short* Cp = (unsigned short*)Cout + row * (size_t)ldc + col;
#pragma unroll
                for (int q = 0; q < 4; q++) {
                    float v = acc[i][j][q];
                    if (region == 0)      v = expf(fminf(v, 60.f));
                    else if (region == 2) v = 1.f / (1.f + expf(-v));
                    Cp[(size_t)q * ldc] = f2bf(v);
                }
            }
        }
    }
}

// ================= phase-structured 128x256 BK=64 GEMM =================
// C[r,c] = sum_k A[r,k]*Bw[c,k].  A rows: BM=128 (bx), B rows: BN=256 (by).
// 512 threads = 8 waves (2 M x 4 N), per-wave 64x64 output, acc[4][4].
// LDS: 2 slots x (A 16KB + B 32KB) = 96KB dynamic.
// T2 swizzle: LDS[row][cb'] holds global[row][cb' ^ ((row&7)<<4)].
// T3-lite: prefetch tile t+1 at phase0 of t; vmcnt(0)+barrier once per tile.
template <int MODE>
__global__ __launch_bounds__(512) void gemm8(const unsigned short* __restrict__ Ag,
                                             const unsigned short* __restrict__ Bg,
                                             void* __restrict__ Cout,
                                             int ldc, int K, int gy) {
    extern __shared__ char smem[];
    const int tid  = threadIdx.x;
    const int lane = tid & 63;
    const int wid  = tid >> 6;
    const int wr   = wid >> 2;      // 0..1
    const int wc   = wid & 3;       // 0..3

    // XCD-aware bijective remap (grid is 1-D, gridDim.x % 8 == 0)
    const int ntot = gridDim.x;
    const int lin  = blockIdx.x;
    const int n2   = (lin & 7) * (ntot >> 3) + (lin >> 3);
    const int bx   = n2 / gy;
    const int by   = n2 % gy;
    const size_t m0 = (size_t)bx * 128;
    const size_t n0 = (size_t)by * 256;

    const size_t K2    = (size_t)K * 2;     // bytes per row
    const size_t gstep = 64 * K2;           // 64 rows per gload

    // staging source (inverse-swizzled): thread covers LDS linear o = g*8192 + tid*16
    const int    r8  = tid >> 3;                                    // row within 64-row group
    const int    cbx = ((tid & 7) << 4) ^ ((r8 & 7) << 4);          // swizzled byte-in-row
    const char*  srcA = (const char*)Ag + (m0 + (size_t)r8) * K2 + cbx;
    const char*  srcB = (const char*)Bg + (n0 + (size_t)r8) * K2 + cbx;

    // ds_read addressing
    const int wrowA = wr * 64 + (lane & 15);
    const int wrowB = wc * 64 + (lane & 15);
    const int kseg  = (lane >> 4) << 4;      // 16B chunk within 64B half-row
    const int lxor  = (lane & 7) << 4;       // swizzle term (row&7 == lane&7)

    f32x4 acc[4][4] = {};

    // prologue: stage tile 0 into slot 0
    {
        char* dA = smem + (tid << 4);
        GLL16(srcA,             dA);
        GLL16(srcA + gstep,     dA + 8192);
        char* dB = dA + 16384;
        GLL16(srcB,             dB);
        GLL16(srcB + gstep,     dB + 8192);
        GLL16(srcB + 2 * gstep, dB + 16384);
        GLL16(srcB + 3 * gstep, dB + 24576);
        asm volatile("s_waitcnt vmcnt(0)" ::: "memory");
        __builtin_amdgcn_s_barrier();
    }

    const int NT = K >> 6;   // 16
#pragma unroll 1
    for (int t = 0; t < NT; ++t) {
        const int s = t & 1;
        const char* sAb = smem + s * 49152;
        const char* sBb = sAb + 16384;

        // ---- phase 0: prefetch t+1, read B(all)+A(i=0,1), MFMA i=0,1 ----
        if (t + 1 < NT) {
            const char* aS = srcA + ((size_t)(t + 1) << 7);
            const char* bS = srcB + ((size_t)(t + 1) << 7);
            char* dA = smem + (s ^ 1) * 49152 + (tid << 4);
            GLL16(aS,             dA);
            GLL16(aS + gstep,     dA + 8192);
            char* dB = dA + 16384;
            GLL16(bS,             dB);
            GLL16(bS + gstep,     dB + 8192);
            GLL16(bS + 2 * gstep, dB + 16384);
            GLL16(bS + 3 * gstep, dB + 24576);
        }

        bf16x8 b0[4], b1[4], a0[2], a1[2];
#pragma unroll
        for (int j = 0; j < 4; ++j) {
            int row = wrowB * 128 + j * 2048;
            b0[j] = __builtin_bit_cast(bf16x8, *(const short8*)(sBb + row + ((     kseg) ^ lxor)));
            b1[j] = __builtin_bit_cast(bf16x8, *(const short8*)(sBb + row + ((64 + kseg) ^ lxor)));
        }
#pragma unroll
        for (int ii = 0; ii < 2; ++ii) {
            int row = wrowA * 128 + ii * 2048;
            a0[ii] = __builtin_bit_cast(bf16x8, *(const short8*)(sAb + row + ((     kseg) ^ lxor)));
            a1[ii] = __builtin_bit_cast(bf16x8, *(const short8*)(sAb + row + ((64 + kseg) ^ lxor)));
        }
        __builtin_amdgcn_s_barrier();
        __builtin_amdgcn_s_setprio(1);
#pragma unroll
        for (int j = 0; j < 4; ++j) {
            acc[0][j] = __builtin_amdgcn_mfma_f32_16x16x32_bf16(a0[0], b0[j], acc[0][j], 0, 0, 0);
            acc[0][j] = __builtin_amdgcn_mfma_f32_16x16x32_bf16(a1[0], b1[j], acc[0][j], 0, 0, 0);
            acc[1][j] = __builtin_amdgcn_mfma_f32_16x16x32_bf16(a0[1], b0[j], acc[1][j], 0, 0, 0);
            acc[1][j] = __builtin_amdgcn_mfma_f32_16x16x32_bf16(a1[1], b1[j], acc[1][j], 0, 0, 0);
        }
        __builtin_amdgcn_s_setprio(0);
        __builtin_amdgcn_s_barrier();

        // ---- phase 1: read A(i=2,3), MFMA i=2,3, end-of-tile sync ----
#pragma unroll
        for (int ii = 0; ii < 2; ++ii) {
            int row = wrowA * 128 + (ii + 2) * 2048;
            a0[ii] = __builtin_bit_cast(bf16x8, *(const short8*)(sAb + row + ((     kseg) ^ lxor)));
            a1[ii] = __builtin_bit_cast(bf16x8, *(const short8*)(sAb + row + ((64 + kseg) ^ lxor)));
        }
        __builtin_amdgcn_s_barrier();
        __builtin_amdgcn_s_setprio(1);
#pragma unroll
        for (int j = 0; j < 4; ++j) {
            acc[2][j] = __builtin_amdgcn_mfma_f32_16x16x32_bf16(a0[0], b0[j], acc[2][j], 0, 0, 0);
            acc[2][j] = __builtin_amdgcn_mfma_f32_16x16x32_bf16(a1[0], b1[j], acc[2][j], 0, 0, 0);
            acc[3][j] = __builtin_amdgcn_mfma_f32_16x16x32_bf16(a0[1], b0[j], acc[3][j], 0, 0, 0);
            acc[3][j] = __builtin_amdgcn_mfma_f32_16x16x32_bf16(a1[1], b1[j], acc[3][j], 0, 0, 0);
        }
        __builtin_amdgcn_s_setprio(0);
        asm volatile("s_waitcnt vmcnt(0)" ::: "memory");
        __builtin_amdgcn_s_barrier();
    }

    const int region = (int)(m0 >> 10);
#pragma unroll
    for (int i = 0; i < 4; i++) {
#pragma unroll
        for (int j = 0; j < 4; j++) {
            size_t row = m0 + wr * 64 + i * 16 + ((lane >> 4) << 2);
            size_t col = n0 + wc * 64 + j * 16 + (lane & 15);
            if constexpr (MODE == 0) {
                float* Cp = (float*)Cout + row * (size_t)ldc + col;
#pragma unroll
                for (int q = 0; q < 4; q++) Cp[(size_t)q * ldc] = acc[i][j][q];
            } else {
                unsigned short* Cp = (unsigned short*)Cout + row * (size_t)ldc + col;
#pragma unroll
                for (int q = 0; q < 4; q++) {
                    float v = acc[i][j][q];
                    if (region == 0)      v = expf(fminf(v, 60.f));
                    else if (region == 2) v = 1.f / (1.f + expf(-v));
                    Cp[(size_t)q * ldc] = f2bf(v);
                }
            }
        }
    }
}

// ---- chunked WKV scan on transposed bf16 projections ----
__global__ __launch_bounds__(256) void wkv_scan_t(const unsigned short* __restrict__ kt,
                                                  const float* __restrict__ td,
                                                  const float* __restrict__ tf,
                                                  unsigned short* __restrict__ rwkv) {
    const int T = CTX_T, C = CDIM, M = MTOT;
    const int CW = 16, CH = 16, L = T / CH;   // 48 steps/chunk
    int bb = blockIdx.x >> 6;
    int cg = blockIdx.x & 63;
    int cl = threadIdx.x & 15;
    int j  = threadIdx.x >> 4;
    int c  = cg * CW + cl;

    float ed    = expf(td[c]);
    float dec   = expf(-ed);
    float wself = expf(tf[c]);

    const unsigned short* rk = kt + (size_t)c * M + bb * T + j * L;
    const unsigned short* rv = rk + (size_t)C * M;
    const unsigned short* rr = rk + (size_t)2 * C * M;

    float A = 0.f, Bs = 0.f;
#pragma unroll
    for (int ib = 0; ib < L; ib += 8) {
        short8 kb = *(const short8*)(rk + ib);
        short8 vb = *(const short8*)(rv + ib);
#pragma unroll
        for (int e = 0; e < 8; e++) {
            float kk = bf2f((unsigned short)kb[e]);
            float vv = bf2f((unsigned short)vb[e]);
            A  = dec * A + kk * vv;
            Bs = dec * Bs + kk;
        }
    }

    __shared__ float sA[CH][CW], sB[CH][CW];
    sA[j][cl] = A; sB[j][cl] = Bs;
    __syncthreads();

    if (threadIdx.x < CW) {
        float dL = expf(-ed * (float)L);
        float cA = 0.f, cB = 0.f;
#pragma unroll
        for (int q = 0; q < CH; q++) {
            float tA = sA[q][cl], tB = sB[q][cl];
            sA[q][cl] = cA; sB[q][cl] = cB;
            cA = dL * cA + tA;
            cB = dL * cB + tB;
        }
    }
    __syncthreads();
    A = sA[j][cl]; Bs = sB[j][cl];

    unsigned short* op = rwkv + ((size_t)(bb * T + j * L)) * C + c;
#pragma unroll
    for (int ib = 0; ib < L; ib += 8) {
        short8 kb = *(const short8*)(rk + ib);
        short8 vb = *(const short8*)(rv + ib);
        short8 rb = *(const short8*)(rr + ib);
#pragma unroll
        for (int e = 0; e < 8; e++) {
            float kk = bf2f((unsigned short)kb[e]);
            float vv = bf2f((unsigned short)vb[e]);
            float sg = bf2f((unsigned short)rb[e]);
            float kv  = kk * vv;
            float num = wself * kv + A;
            float den = wself * kk + Bs + 1e-9f;
            op[(size_t)(ib + e) * C] = f2bf(sg * num / den);
            A  = dec * A + kv;
            Bs = dec * Bs + kk;
        }
    }
}

extern "C" void kernel_launch(void* const* d_in, const int* in_sizes, int n_in,
                              void* d_out, int out_size, void* d_ws, size_t ws_size,
                              hipStream_t stream) {
    const float* x  = (const float*)d_in[0];
    const float* td = (const float*)d_in[1];
    const float* tf = (const float*)d_in[2];
    const float* tm = (const float*)d_in[3];
    const float* Wk = (const float*)d_in[4];
    const float* Wv = (const float*)d_in[5];
    const float* Wr = (const float*)d_in[6];
    const float* Wo = (const float*)d_in[7];
    float* out = (float*)d_out;

    const int B = BDIM, T = CTX_T, C = CDIM;
    const size_t M = (size_t)B * T;   // 6144

    size_t off = 0;
    auto carve = [&](size_t bytes) -> void* {
        void* p = (char*)d_ws + off;
        off += (bytes + 255) & ~(size_t)255;
        return p;
    };
    unsigned short* xm   = (unsigned short*)carve(M * C * 2);
    unsigned short* wall = (unsigned short*)carve((size_t)4 * C * C * 2);
    unsigned short* kvrT = (unsigned short*)carve((size_t)3 * C * M * 2);
    unsigned short* rwkv = (unsigned short*)carve(M * C * 2);
    unsigned short* wkvr = wall;
    unsigned short* wo   = wall + (size_t)3 * C * C;

    cvt4<<<(4 * C * C) / 4 / 256, 256, 0, stream>>>(Wk, Wv, Wr, Wo, wall);

    const int total = (int)(M * C);
    mix_bf16<<<total / 4 / 256, 256, 0, stream>>>(x, tm, xm, total);

    const int LDS8 = 96 * 1024;
    hipError_t e1 = hipFuncSetAttribute((const void*)gemm8<2>,
                                        hipFuncAttributeMaxDynamicSharedMemorySize, LDS8);
    hipError_t e2 = hipFuncSetAttribute((const void*)gemm8<0>,
                                        hipFuncAttributeMaxDynamicSharedMemorySize, LDS8);
    const bool use8 = (e1 == hipSuccess) && (e2 == hipSuccess);

    if (use8) {
        // GEMM1: kvrT[3C][M]; A = weights (24 tiles of 128), B = xm (24 tiles of 256)
        gemm8<2><<<24 * 24, 512, LDS8, stream>>>(wkvr, xm, kvrT, (int)M, C, 24);
    } else {
        dim3 g1(24u, 48u);
        gemm_bt<2><<<g1, 256, 0, stream>>>(wkvr, xm, kvrT, (int)M, C);
    }

    wkv_scan_t<<<B * (C / 16), 256, 0, stream>>>(kvrT, td, tf, rwkv);

    if (use8) {
        // GEMM2: out[M][C] f32; A = rwkv (48 tiles of 128), B = Wo (4 tiles of 256)
        gemm8<0><<<48 * 4, 512, LDS8, stream>>>(rwkv, wo, out, C, C, 4);
    } else {
        dim3 g2(48u, 8u);
        gemm_bt<0><<<g2, 256, 0, stream>>>(rwkv, wo, out, C, C);
    }
}

// Round 5
// 129.051 us; speedup vs baseline: 1.1321x; 1.1321x over previous
//
#include <hip/hip_runtime.h>

#define CTX_T 768
#define CDIM  1024
#define BDIM  8
#define MTOT  (BDIM * CTX_T)   // 6144

typedef __attribute__((ext_vector_type(8))) __bf16 bf16x8;
typedef __attribute__((ext_vector_type(8))) short short8;
typedef __attribute__((ext_vector_type(4))) float f32x4;

__device__ inline unsigned short f2bf(float f) {
    union { float f; unsigned u; } v; v.f = f;
    unsigned r = v.u + 0x7fffu + ((v.u >> 16) & 1u);
    return (unsigned short)(r >> 16);
}
__device__ inline float bf2f(unsigned short u) {
    union { unsigned u; float f; } v; v.u = ((unsigned)u) << 16; return v.f;
}

// ---- fused f32 -> bf16 converter for the 4 weight matrices ----
__global__ void cvt4(const float* __restrict__ s0, const float* __restrict__ s1,
                     const float* __restrict__ s2, const float* __restrict__ s3,
                     unsigned short* __restrict__ d) {
    int i = (blockIdx.x * blockDim.x + threadIdx.x) * 4;
    const int SEG = 1 << 20;
    const float* s = (i < SEG) ? s0 : (i < 2 * SEG) ? s1 : (i < 3 * SEG) ? s2 : s3;
    float4 f = *(const float4*)(s + (i & (SEG - 1)));
    ushort4 o;
    o.x = f2bf(f.x); o.y = f2bf(f.y); o.z = f2bf(f.z); o.w = f2bf(f.w);
    *(ushort4*)(d + i) = o;
}

// ---- time-shift + mix, f32 in -> bf16 out ----
__global__ void mix_bf16(const float* __restrict__ x, const float* __restrict__ tm,
                         unsigned short* __restrict__ xm, int total) {
    int i = (blockIdx.x * blockDim.x + threadIdx.x) * 4;
    if (i >= total) return;
    int c  = i & (CDIM - 1);
    int bt = i >> 10;
    int t  = bt % CTX_T;
    float4 xc  = *(const float4*)(x + i);
    float4 tmc = *(const float4*)(tm + c);
    float4 xp = make_float4(0.f, 0.f, 0.f, 0.f);
    if (t > 0) xp = *(const float4*)(x + i - CDIM);
    ushort4 o;
    o.x = f2bf(xc.x * tmc.x + xp.x * (1.f - tmc.x));
    o.y = f2bf(xc.y * tmc.y + xp.y * (1.f - tmc.y));
    o.z = f2bf(xc.z * tmc.z + xp.z * (1.f - tmc.z));
    o.w = f2bf(xc.w * tmc.w + xp.w * (1.f - tmc.w));
    *(ushort4*)(xm + i) = o;
}

// ---- bf16 MFMA GEMM: C[r,c] = sum_k A[r,k] * Bw[c,k]  (both row-major, B^T form) ----
// 128x128 tile, BK=32, 4 waves (2x2), 64x64 per wave, 4x4 16x16x32 frags. (m97 structure)
// MODE 0: plain f32 row-major [rowsA][ldc] output.
// MODE 3: bf16 row-major output with COLUMN-region transform (region = n0>>10, block-uniform):
//         col <  C  -> exp(min(v,60))   (k cols)
//         col < 2C  -> identity          (v cols)
//         else      -> sigmoid(v)        (r cols)
#define GLL16(GP, LP) __builtin_amdgcn_global_load_lds(                        \
    (__attribute__((address_space(1))) void*)(void*)(GP),                     \
    (__attribute__((address_space(3))) void*)(void*)(LP), 16, 0, 0)

template <int MODE>
__global__ __launch_bounds__(256) void gemm_bt(const unsigned short* __restrict__ A,
                                               const unsigned short* __restrict__ Bw,
                                               void* __restrict__ Cout,
                                               int ldc, int K) {
    __shared__ unsigned short lA[128 * 32];
    __shared__ unsigned short lB[128 * 32];
    const int tid  = threadIdx.x;
    const int lane = tid & 63;
    const int wid  = tid >> 6;
    const int wr   = wid >> 1, wc = wid & 1;
    const size_t m0 = (size_t)blockIdx.x * 128;
    const size_t n0 = (size_t)blockIdx.y * 128;

    const unsigned short* gA = A + (m0 + (size_t)(tid >> 2)) * K + ((tid & 3) << 3);
    const unsigned short* gB = Bw + (n0 + (size_t)(tid >> 2)) * K + ((tid & 3) << 3);
    char* sA = (char*)lA + tid * 16;
    char* sB = (char*)lB + tid * 16;

    f32x4 acc[4][4] = {};

    for (int k0 = 0; k0 < K; k0 += 32) {
        GLL16(gA + k0,             sA);
        GLL16(gA + k0 + 64 * K,    sA + 4096);
        GLL16(gB + k0,             sB);
        GLL16(gB + k0 + 64 * K,    sB + 4096);
        __syncthreads();

        const unsigned short* pA = lA + (wr * 64 + (lane & 15)) * 32 + ((lane >> 4) << 3);
        const unsigned short* pB = lB + (wc * 64 + (lane & 15)) * 32 + ((lane >> 4) << 3);
        bf16x8 a[4], b[4];
#pragma unroll
        for (int i = 0; i < 4; i++) {
            a[i] = __builtin_bit_cast(bf16x8, *(const short8*)(pA + i * 16 * 32));
            b[i] = __builtin_bit_cast(bf16x8, *(const short8*)(pB + i * 16 * 32));
        }
#pragma unroll
        for (int i = 0; i < 4; i++)
#pragma unroll
            for (int j = 0; j < 4; j++)
                acc[i][j] = __builtin_amdgcn_mfma_f32_16x16x32_bf16(a[i], b[j], acc[i][j], 0, 0, 0);
        __syncthreads();
    }

    const int region = (int)(n0 >> 10);   // 0:k 1:v 2:r (MODE 3; col tiles never straddle C)
#pragma unroll
    for (int i = 0; i < 4; i++) {
#pragma unroll
        for (int j = 0; j < 4; j++) {
            size_t row = m0 + wr * 64 + i * 16 + ((lane >> 4) << 2);
            size_t col = n0 + wc * 64 + j * 16 + (lane & 15);
            if constexpr (MODE == 0) {
                float* Cp = (float*)Cout + row * (size_t)ldc + col;
#pragma unroll
                for (int q = 0; q < 4; q++) Cp[(size_t)q * ldc] = acc[i][j][q];
            } else {
                unsigned short* Cp = (unsigned short*)Cout + row * (size_t)ldc + col;
#pragma unroll
                for (int q = 0; q < 4; q++) {
                    float v = acc[i][j][q];
                    if (region == 0)      v = expf(fminf(v, 60.f));
                    else if (region == 2) v = 1.f / (1.f + expf(-v));
                    Cp[(size_t)q * ldc] = f2bf(v);
                }
            }
        }
    }
}

// ---- segment-parallel WKV scan on [M][3C] bf16 (k pre-exp'd, r pre-sigmoid'd) ----
// dec = exp(-exp(td)) <= 0.51 -> dec^64 < 1e-18: a 64-step redundant warmup makes
// T-segments independent (exact at t0=0). One pass, no barriers, wave-coalesced reads
// (64 lanes = 64 consecutive channels -> one 128B line per load).
// Block: 256 thr = 64 channels x 4 segment-units. Grid: 8b x 16cg x 3sg = 384.
__global__ __launch_bounds__(256) void wkv_seg(const unsigned short* __restrict__ kvr,
                                               const float* __restrict__ td,
                                               const float* __restrict__ tf,
                                               unsigned short* __restrict__ rwkv) {
    const int C = CDIM;
    int bid  = blockIdx.x;
    int sg   = bid % 3;
    int cg   = (bid / 3) & 15;
    int b    = bid / 48;
    int lane = threadIdx.x & 63;
    int su   = threadIdx.x >> 6;
    int t0   = (sg * 4 + su) * 64;        // segment start (0..704)
    int c    = cg * 64 + lane;

    float ed  = expf(td[c]);
    float dec = expf(-ed);
    float ws  = expf(tf[c]);

    const unsigned short* base = kvr + (size_t)b * CTX_T * 3 * C + c;

    float A = 0.f, Bs = 0.f;
    int tw = t0 - 64; if (tw < 0) tw = 0;
#pragma unroll 8
    for (int t = tw; t < t0; ++t) {
        const unsigned short* p = base + (size_t)t * (3 * C);
        float kk = bf2f(p[0]);
        float vv = bf2f(p[C]);
        A  = dec * A + kk * vv;
        Bs = dec * Bs + kk;
    }

    unsigned short* op = rwkv + ((size_t)b * CTX_T + t0) * C + c;
#pragma unroll 8
    for (int i = 0; i < 64; ++i) {
        const unsigned short* p = base + (size_t)(t0 + i) * (3 * C);
        float kk = bf2f(p[0]);
        float vv = bf2f(p[C]);
        float sr = bf2f(p[2 * C]);
        float kv  = kk * vv;
        float num = ws * kv + A;
        float den = ws * kk + Bs + 1e-9f;
        op[(size_t)i * C] = f2bf(sr * num / den);
        A  = dec * A + kv;
        Bs = dec * Bs + kk;
    }
}

extern "C" void kernel_launch(void* const* d_in, const int* in_sizes, int n_in,
                              void* d_out, int out_size, void* d_ws, size_t ws_size,
                              hipStream_t stream) {
    const float* x  = (const float*)d_in[0];
    const float* td = (const float*)d_in[1];
    const float* tf = (const float*)d_in[2];
    const float* tm = (const float*)d_in[3];
    const float* Wk = (const float*)d_in[4];
    const float* Wv = (const float*)d_in[5];
    const float* Wr = (const float*)d_in[6];
    const float* Wo = (const float*)d_in[7];
    float* out = (float*)d_out;

    const int B = BDIM, T = CTX_T, C = CDIM;
    const size_t M = (size_t)B * T;   // 6144

    size_t off = 0;
    auto carve = [&](size_t bytes) -> void* {
        void* p = (char*)d_ws + off;
        off += (bytes + 255) & ~(size_t)255;
        return p;
    };
    unsigned short* xm   = (unsigned short*)carve(M * C * 2);                 // [M][C] bf16 mixed input
    unsigned short* wall = (unsigned short*)carve((size_t)4 * C * C * 2);     // [Wk;Wv;Wr;Wo] bf16
    unsigned short* kvr  = (unsigned short*)carve(M * 3 * C * 2);             // [M][3C] bf16 transformed proj
    unsigned short* rwkv = (unsigned short*)carve(M * C * 2);                 // [M][C] bf16 gated output
    unsigned short* wkvr = wall;
    unsigned short* wo   = wall + (size_t)3 * C * C;

    cvt4<<<(4 * C * C) / 4 / 256, 256, 0, stream>>>(Wk, Wv, Wr, Wo, wall);

    const int total = (int)(M * C);
    mix_bf16<<<total / 4 / 256, 256, 0, stream>>>(x, tm, xm, total);

    // GEMM1 (R1 orientation): kvr[m][n] = sum_k xm[m,k] * W[n,k], bf16 out + col transforms
    dim3 g1((unsigned)(M / 128), (unsigned)(3 * C / 128));   // 48 x 24
    gemm_bt<3><<<g1, 256, 0, stream>>>(xm, wkvr, kvr, 3 * C, C);

    wkv_seg<<<B * 16 * 3, 256, 0, stream>>>(kvr, td, tf, rwkv);

    // GEMM2: out[m][d] = sum_c rwkv[m,c] * Wo[d,c], f32 out
    dim3 g2((unsigned)(M / 128), (unsigned)(C / 128));       // 48 x 8
    gemm_bt<0><<<g2, 256, 0, stream>>>(rwkv, wo, out, C, C);
}

// Round 6
// 120.993 us; speedup vs baseline: 1.2075x; 1.0666x over previous
//
#include <hip/hip_runtime.h>

#define CTX_T 768
#define CDIM  1024
#define BDIM  8
#define MTOT  (BDIM * CTX_T)   // 6144

typedef __attribute__((ext_vector_type(8))) __bf16 bf16x8;
typedef __attribute__((ext_vector_type(8))) short short8;
typedef __attribute__((ext_vector_type(4))) float f32x4;

__device__ inline unsigned short f2bf(float f) {
    union { float f; unsigned u; } v; v.f = f;
    unsigned r = v.u + 0x7fffu + ((v.u >> 16) & 1u);
    return (unsigned short)(r >> 16);
}
__device__ inline float bf2f(unsigned short u) {
    union { unsigned u; float f; } v; v.u = ((unsigned)u) << 16; return v.f;
}

// ---- fused f32 -> bf16 converter for the 4 weight matrices ----
__global__ void cvt4(const float* __restrict__ s0, const float* __restrict__ s1,
                     const float* __restrict__ s2, const float* __restrict__ s3,
                     unsigned short* __restrict__ d) {
    int i = (blockIdx.x * blockDim.x + threadIdx.x) * 4;
    const int SEG = 1 << 20;
    const float* s = (i < SEG) ? s0 : (i < 2 * SEG) ? s1 : (i < 3 * SEG) ? s2 : s3;
    float4 f = *(const float4*)(s + (i & (SEG - 1)));
    ushort4 o;
    o.x = f2bf(f.x); o.y = f2bf(f.y); o.z = f2bf(f.z); o.w = f2bf(f.w);
    *(ushort4*)(d + i) = o;
}

// ---- time-shift + mix, f32 in -> bf16 out ----
__global__ void mix_bf16(const float* __restrict__ x, const float* __restrict__ tm,
                         unsigned short* __restrict__ xm, int total) {
    int i = (blockIdx.x * blockDim.x + threadIdx.x) * 4;
    if (i >= total) return;
    int c  = i & (CDIM - 1);
    int bt = i >> 10;
    int t  = bt % CTX_T;
    float4 xc  = *(const float4*)(x + i);
    float4 tmc = *(const float4*)(tm + c);
    float4 xp = make_float4(0.f, 0.f, 0.f, 0.f);
    if (t > 0) xp = *(const float4*)(x + i - CDIM);
    ushort4 o;
    o.x = f2bf(xc.x * tmc.x + xp.x * (1.f - tmc.x));
    o.y = f2bf(xc.y * tmc.y + xp.y * (1.f - tmc.y));
    o.z = f2bf(xc.z * tmc.z + xp.z * (1.f - tmc.z));
    o.w = f2bf(xc.w * tmc.w + xp.w * (1.f - tmc.w));
    *(ushort4*)(xm + i) = o;
}

#define GLL16(GP, LP) __builtin_amdgcn_global_load_lds(                        \
    (__attribute__((address_space(1))) void*)(void*)(GP),                     \
    (__attribute__((address_space(3))) void*)(void*)(LP), 16, 0, 0)

// ================ m97 2-barrier skeleton, BM=128 BN=256 BK=64, 8 waves ================
// C[r,c] = sum_k A[r,k] * Bw[c,k]  (row-major, B^T form), K multiple of 64.
// 512 threads = 8 waves (2 M x 4 N), per-wave 64x64 out, acc[4][4] of 16x16x32 frags.
// LDS 48KB single-buffer: lA[128][64], lB[256][64] bf16, row = 128 bytes.
// T2 swizzle (R4-verified): LDS[r][cb] holds global[r][cb ^ ((r&7)<<4)]; gload_lds dest
// linear, source pre-inverse-swizzled; ds_read applies the same XOR. Zero bank conflicts.
// MODE 0: f32 row-major out. MODE 3: bf16 out + column-region transform (region=n0>>10):
//         col < C -> exp(min(v,60)) ; col < 2C -> identity ; else -> sigmoid(v)
template <int MODE>
__global__ __launch_bounds__(512, 4) void gemm_w8(const unsigned short* __restrict__ A,
                                                  const unsigned short* __restrict__ Bw,
                                                  void* __restrict__ Cout,
                                                  int ldc, int K) {
    __shared__ unsigned short lA[128 * 64];   // 16 KB
    __shared__ unsigned short lB[256 * 64];   // 32 KB
    const int tid  = threadIdx.x;
    const int lane = tid & 63;
    const int wid  = tid >> 6;
    const int wr   = wid >> 2;      // 0..1  (M)
    const int wc   = wid & 3;       // 0..3  (N)
    const size_t m0 = (size_t)blockIdx.x * 128;
    const size_t n0 = (size_t)blockIdx.y * 256;

    const size_t K2 = (size_t)K * 2;          // bytes per global row
    // staging: thread covers LDS byte o = g*8192 + tid*16 -> row r = g*64 + (tid>>3),
    // byte-in-row (tid&7)*16; source col-byte pre-inverse-swizzled by ((r&7)<<4).
    const int   r8  = tid >> 3;                               // row within 64-row group
    const int   cbs = ((tid & 7) << 4) ^ ((r8 & 7) << 4);     // swizzled byte within k-window
    const char* srcA = (const char*)A + (m0 + (size_t)r8) * K2 + cbs;
    const char* srcB = (const char*)Bw + (n0 + (size_t)r8) * K2 + cbs;
    char* dA = (char*)lA + (size_t)tid * 16;
    char* dB = (char*)lB + (size_t)tid * 16;
    const size_t gstep = 64 * K2;             // 64 global rows per gload

    // ds_read addressing: row stride 128B, swizzle XOR on byte-in-row
    const int rbA = (wr * 64 + (lane & 15)) << 7;   // A fragment base (row*128)
    const int rbB = (wc * 64 + (lane & 15)) << 7;   // B fragment base
    const int ksegbase = (lane >> 4) << 4;          // 16B chunk within 64B half
    const int lxor = (lane & 7) << 4;               // row&7 == lane&7 for frag rows

    f32x4 acc[4][4] = {};

    for (int t = 0; t < (K >> 6); ++t) {
        const size_t kb = (size_t)t << 7;   // 128 bytes per K-tile window
        GLL16(srcA + kb,             dA);
        GLL16(srcA + kb + gstep,     dA + 8192);
        GLL16(srcB + kb,             dB);
        GLL16(srcB + kb + gstep,     dB + 8192);
        GLL16(srcB + kb + 2 * gstep, dB + 16384);
        GLL16(srcB + kb + 3 * gstep, dB + 24576);
        __syncthreads();

#pragma unroll
        for (int kk = 0; kk < 2; ++kk) {
            const int ko = kk * 64 + ksegbase;
            bf16x8 a[4], b[4];
#pragma unroll
            for (int i = 0; i < 4; ++i)
                a[i] = __builtin_bit_cast(bf16x8,
                    *(const short8*)((const char*)lA + rbA + i * 2048 + (ko ^ lxor)));
#pragma unroll
            for (int j = 0; j < 4; ++j)
                b[j] = __builtin_bit_cast(bf16x8,
                    *(const short8*)((const char*)lB + rbB + j * 2048 + (ko ^ lxor)));
#pragma unroll
            for (int i = 0; i < 4; ++i)
#pragma unroll
                for (int j = 0; j < 4; ++j)
                    acc[i][j] = __builtin_amdgcn_mfma_f32_16x16x32_bf16(a[i], b[j], acc[i][j], 0, 0, 0);
        }
        __syncthreads();
    }

    const int region = (int)(n0 >> 10);   // MODE 3: 0:k 1:v 2:r (256-col tiles never straddle C)
#pragma unroll
    for (int i = 0; i < 4; i++) {
#pragma unroll
        for (int j = 0; j < 4; j++) {
            size_t row = m0 + wr * 64 + i * 16 + ((lane >> 4) << 2);
            size_t col = n0 + wc * 64 + j * 16 + (lane & 15);
            if constexpr (MODE == 0) {
                float* Cp = (float*)Cout + row * (size_t)ldc + col;
#pragma unroll
                for (int q = 0; q < 4; q++) Cp[(size_t)q * ldc] = acc[i][j][q];
            } else {
                unsigned short* Cp = (unsigned short*)Cout + row * (size_t)ldc + col;
#pragma unroll
                for (int q = 0; q < 4; q++) {
                    float v = acc[i][j][q];
                    if (region == 0)      v = expf(fminf(v, 60.f));
                    else if (region == 2) v = 1.f / (1.f + expf(-v));
                    Cp[(size_t)q * ldc] = f2bf(v);
                }
            }
        }
    }
}

// ---- segment-parallel WKV scan on [M][3C] bf16 (k pre-exp'd, r pre-sigmoid'd) ----
// dec = exp(-exp(td)) <= 0.51 -> dec^64 < 1e-18: 64-step redundant warmup makes
// T-segments independent. Wave-coalesced reads (64 lanes = consecutive channels).
__global__ __launch_bounds__(256) void wkv_seg(const unsigned short* __restrict__ kvr,
                                               const float* __restrict__ td,
                                               const float* __restrict__ tf,
                                               unsigned short* __restrict__ rwkv) {
    const int C = CDIM;
    int bid  = blockIdx.x;
    int sg   = bid % 3;
    int cg   = (bid / 3) & 15;
    int b    = bid / 48;
    int lane = threadIdx.x & 63;
    int su   = threadIdx.x >> 6;
    int t0   = (sg * 4 + su) * 64;        // segment start (0..704)
    int c    = cg * 64 + lane;

    float ed  = expf(td[c]);
    float dec = expf(-ed);
    float ws  = expf(tf[c]);

    const unsigned short* base = kvr + (size_t)b * CTX_T * 3 * C + c;

    float A = 0.f, Bs = 0.f;
    int tw = t0 - 64; if (tw < 0) tw = 0;
#pragma unroll 8
    for (int t = tw; t < t0; ++t) {
        const unsigned short* p = base + (size_t)t * (3 * C);
        float kk = bf2f(p[0]);
        float vv = bf2f(p[C]);
        A  = dec * A + kk * vv;
        Bs = dec * Bs + kk;
    }

    unsigned short* op = rwkv + ((size_t)b * CTX_T + t0) * C + c;
#pragma unroll 8
    for (int i = 0; i < 64; ++i) {
        const unsigned short* p = base + (size_t)(t0 + i) * (3 * C);
        float kk = bf2f(p[0]);
        float vv = bf2f(p[C]);
        float sr = bf2f(p[2 * C]);
        float kv  = kk * vv;
        float num = ws * kv + A;
        float den = ws * kk + Bs + 1e-9f;
        op[(size_t)i * C] = f2bf(sr * num / den);
        A  = dec * A + kv;
        Bs = dec * Bs + kk;
    }
}

extern "C" void kernel_launch(void* const* d_in, const int* in_sizes, int n_in,
                              void* d_out, int out_size, void* d_ws, size_t ws_size,
                              hipStream_t stream) {
    const float* x  = (const float*)d_in[0];
    const float* td = (const float*)d_in[1];
    const float* tf = (const float*)d_in[2];
    const float* tm = (const float*)d_in[3];
    const float* Wk = (const float*)d_in[4];
    const float* Wv = (const float*)d_in[5];
    const float* Wr = (const float*)d_in[6];
    const float* Wo = (const float*)d_in[7];
    float* out = (float*)d_out;

    const int B = BDIM, T = CTX_T, C = CDIM;
    const size_t M = (size_t)B * T;   // 6144

    size_t off = 0;
    auto carve = [&](size_t bytes) -> void* {
        void* p = (char*)d_ws + off;
        off += (bytes + 255) & ~(size_t)255;
        return p;
    };
    unsigned short* xm   = (unsigned short*)carve(M * C * 2);                 // [M][C] bf16 mixed input
    unsigned short* wall = (unsigned short*)carve((size_t)4 * C * C * 2);     // [Wk;Wv;Wr;Wo] bf16
    unsigned short* kvr  = (unsigned short*)carve(M * 3 * C * 2);             // [M][3C] bf16 transformed proj
    unsigned short* rwkv = (unsigned short*)carve(M * C * 2);                 // [M][C] bf16 gated output
    unsigned short* wkvr = wall;
    unsigned short* wo   = wall + (size_t)3 * C * C;

    cvt4<<<(4 * C * C) / 4 / 256, 256, 0, stream>>>(Wk, Wv, Wr, Wo, wall);

    const int total = (int)(M * C);
    mix_bf16<<<total / 4 / 256, 256, 0, stream>>>(x, tm, xm, total);

    // GEMM1: kvr[m][n] = sum_k xm[m,k] * W[n,k], bf16 out + col transforms
    dim3 g1((unsigned)(M / 128), (unsigned)(3 * C / 256));   // 48 x 12
    gemm_w8<3><<<g1, 512, 0, stream>>>(xm, wkvr, kvr, 3 * C, C);

    wkv_seg<<<B * 16 * 3, 256, 0, stream>>>(kvr, td, tf, rwkv);

    // GEMM2: out[m][d] = sum_c rwkv[m,c] * Wo[d,c], f32 out
    dim3 g2((unsigned)(M / 128), (unsigned)(C / 256));       // 48 x 4
    gemm_w8<0><<<g2, 512, 0, stream>>>(rwkv, wo, out, C, C);
}